// Round 1
// baseline (643.169 us; speedup 1.0000x reference)
//
#include <hip/hip_runtime.h>
#include <math.h>

#define CCH 64
#define HW 441
#define NB2 25
#define JCHUNK 128
#define TPB 256

// Kernel 1: fold mask + 1/norm into descriptors, transpose to (B, HW, C).
// x: (B, C, HW), mask: (B, HW) -> out: (B, HW, C) with out[b][i][c] = x[b][c][i]*mask[b][i]/||x[b][:][i]||
__global__ void normalize_kernel(const float* __restrict__ x,
                                 const float* __restrict__ mask,
                                 float* __restrict__ out, int total) {
    int idx = blockIdx.x * blockDim.x + threadIdx.x;
    if (idx >= total) return;
    int b = idx / HW;
    int i = idx - b * HW;
    const float* xb = x + (size_t)b * CCH * HW + i;
    float vals[CCH];
    float ss = 0.f;
#pragma unroll
    for (int c = 0; c < CCH; ++c) {
        float v = xb[(size_t)c * HW];   // coalesced: lanes have consecutive i
        vals[c] = v;
        ss += v * v;
    }
    float scale = mask[idx] * rsqrtf(ss);
    float4* ob = (float4*)(out + (size_t)idx * CCH);
#pragma unroll
    for (int c = 0; c < CCH; c += 4) {
        ob[c >> 2] = make_float4(vals[c] * scale, vals[c + 1] * scale,
                                 vals[c + 2] * scale, vals[c + 3] * scale);
    }
}

// Branchless top-3 insertion: 3 max + 2 min per value.
#define TOP3_INSERT(v, t0, t1, t2)                 \
    do {                                           \
        float _m = fmaxf(t0, v);                   \
        float _c = fminf(t0, v);                   \
        t0 = _m;                                   \
        _m = fmaxf(t1, _c);                        \
        _c = fminf(t1, _c);                        \
        t1 = _m;                                   \
        t2 = fmaxf(t2, _c);                        \
    } while (0)

// Kernel 2: one block per (a,b) pair. Each thread owns 2 query rows in
// registers; s-panel streamed through LDS in 128-row chunks; rows read
// wave-uniform (LDS broadcast, conflict-free). Row-wise top-3 fused.
__global__ __launch_bounds__(TPB) void sim_topk_kernel(const float* __restrict__ qh,
                                                       const float* __restrict__ sh,
                                                       float* __restrict__ out) {
    __shared__ float s_lds[JCHUNK * CCH];   // 32 KB
    __shared__ float s_red[TPB / 64];

    int pair = blockIdx.x;
    int a = pair / NB2;
    int b = pair - a * NB2;
    const float* qa = qh + (size_t)a * HW * CCH;
    const float* sb = sh + (size_t)b * HW * CCH;
    int tid = threadIdx.x;

    float q0[CCH], q1[CCH];
    {
        const float4* p0 = (const float4*)(qa + (size_t)tid * CCH);
#pragma unroll
        for (int k = 0; k < CCH / 4; ++k) {
            float4 v = p0[k];
            q0[4 * k + 0] = v.x; q0[4 * k + 1] = v.y;
            q0[4 * k + 2] = v.z; q0[4 * k + 3] = v.w;
        }
        int i1 = tid + TPB;
        if (i1 < HW) {
            const float4* p1 = (const float4*)(qa + (size_t)i1 * CCH);
#pragma unroll
            for (int k = 0; k < CCH / 4; ++k) {
                float4 v = p1[k];
                q1[4 * k + 0] = v.x; q1[4 * k + 1] = v.y;
                q1[4 * k + 2] = v.z; q1[4 * k + 3] = v.w;
            }
        } else {
#pragma unroll
            for (int k = 0; k < CCH; ++k) q1[k] = 0.f;
        }
    }

    const float NEG = -1e30f;
    float t00 = NEG, t01 = NEG, t02 = NEG;
    float t10 = NEG, t11 = NEG, t12 = NEG;

    for (int j0 = 0; j0 < HW; j0 += JCHUNK) {
        int jn = min(JCHUNK, HW - j0);
        __syncthreads();
        {
            const float4* src = (const float4*)(sb + (size_t)j0 * CCH);
            float4* dst = (float4*)s_lds;
            int nf4 = (jn * CCH) >> 2;
            for (int t = tid; t < nf4; t += TPB) dst[t] = src[t];
        }
        __syncthreads();

        for (int jj = 0; jj < jn; ++jj) {
            const float4* srow = (const float4*)(s_lds + jj * CCH);
            float a0x = 0.f, a0y = 0.f, a0z = 0.f, a0w = 0.f;
            float a1x = 0.f, a1y = 0.f, a1z = 0.f, a1w = 0.f;
#pragma unroll
            for (int k = 0; k < CCH / 4; ++k) {
                float4 sv = srow[k];
                a0x += q0[4 * k + 0] * sv.x;
                a0y += q0[4 * k + 1] * sv.y;
                a0z += q0[4 * k + 2] * sv.z;
                a0w += q0[4 * k + 3] * sv.w;
                a1x += q1[4 * k + 0] * sv.x;
                a1y += q1[4 * k + 1] * sv.y;
                a1z += q1[4 * k + 2] * sv.z;
                a1w += q1[4 * k + 3] * sv.w;
            }
            float d0 = (a0x + a0y) + (a0z + a0w);
            float d1 = (a1x + a1y) + (a1z + a1w);
            TOP3_INSERT(d0, t00, t01, t02);
            TOP3_INSERT(d1, t10, t11, t12);
        }
    }

    float partial = t00 + t01 + t02;
    if (tid + TPB < HW) partial += t10 + t11 + t12;

#pragma unroll
    for (int off = 32; off > 0; off >>= 1) partial += __shfl_down(partial, off);
    int lane = tid & 63, w = tid >> 6;
    if (lane == 0) s_red[w] = partial;
    __syncthreads();
    if (tid == 0) {
        float r = 0.f;
#pragma unroll
        for (int i = 0; i < TPB / 64; ++i) r += s_red[i];
        out[pair] = r;
    }
}

extern "C" void kernel_launch(void* const* d_in, const int* in_sizes, int n_in,
                              void* d_out, int out_size, void* d_ws, size_t ws_size,
                              hipStream_t stream) {
    const float* x1 = (const float*)d_in[0];
    const float* x2 = (const float*)d_in[1];
    const float* m1 = (const float*)d_in[2];
    const float* m2 = (const float*)d_in[3];
    float* out = (float*)d_out;

    int B1 = in_sizes[0] / (CCH * HW);
    int B2 = in_sizes[1] / (CCH * HW);

    float* qh = (float*)d_ws;
    float* sh = qh + (size_t)B1 * HW * CCH;

    int n1 = B1 * HW, n2 = B2 * HW;
    normalize_kernel<<<(n1 + 255) / 256, 256, 0, stream>>>(x1, m1, qh, n1);
    normalize_kernel<<<(n2 + 255) / 256, 256, 0, stream>>>(x2, m2, sh, n2);
    sim_topk_kernel<<<B1 * B2, TPB, 0, stream>>>(qh, sh, out);
}

// Round 2
// 127.384 us; speedup vs baseline: 5.0491x; 5.0491x over previous
//
#include <hip/hip_runtime.h>
#include <math.h>

#define CCH 64
#define HW 441
#define HWP 448
#define NT 28          // 448/16 tiles
#define LDSW 72        // padded row stride in halves: 144 B = 16B-aligned, 2-way banks (free)
#define NB2 25
#define TPB 256

typedef _Float16 half8 __attribute__((ext_vector_type(8)));
typedef float f32x4 __attribute__((ext_vector_type(4)));

// ---- kernel 1: fold mask + 1/norm into f16 descriptors, (B,C,HW) -> (B,448,64), pad rows zeroed
__global__ void normalize_f16_kernel(const float* __restrict__ x,
                                     const float* __restrict__ mask,
                                     _Float16* __restrict__ out, int B) {
    int idx = blockIdx.x * blockDim.x + threadIdx.x;
    if (idx >= B * HWP) return;
    int b = idx / HWP;
    int i = idx - b * HWP;
    __align__(16) _Float16 o[CCH];
    if (i < HW) {
        const float* xb = x + (size_t)b * CCH * HW + i;
        float vals[CCH];
        float ss = 0.f;
#pragma unroll
        for (int c = 0; c < CCH; ++c) {
            float v = xb[c * HW];      // coalesced across lanes (consecutive i)
            vals[c] = v;
            ss += v * v;
        }
        float scale = mask[b * HW + i] * rsqrtf(ss);
#pragma unroll
        for (int c = 0; c < CCH; ++c) o[c] = (_Float16)(vals[c] * scale);
    } else {
#pragma unroll
        for (int c = 0; c < CCH; ++c) o[c] = (_Float16)0.f;
    }
    float4* dst = (float4*)(out + (size_t)idx * CCH);
#pragma unroll
    for (int k = 0; k < CCH / 8; ++k) dst[k] = ((const float4*)o)[k];
}

// branchless top-3 insert: 3 max + 2 min
#define TOP3_INSERT(v, t0, t1, t2)        \
    do {                                  \
        float _m = fmaxf(t0, v);          \
        float _c = fminf(t0, v);          \
        t0 = _m;                          \
        _m = fmaxf(t1, _c);               \
        _c = fminf(t1, _c);               \
        t1 = _m;                          \
        t2 = fmaxf(t2, _c);               \
    } while (0)

// merge two sorted triples (t sorted desc, b sorted desc) -> top3 of union in t.
// c0=max(t0,b0); c1=max(min(t0,b0),max(t1,b1)); c2=max(min(min(t0,b0),max(t1,b1)), max(t2,b2))
// (min(t1,b1) provably dominated)
#define MERGE3(t0, t1, t2, b0, b1, b2)            \
    do {                                          \
        float _m0 = fmaxf(t0, b0);                \
        float _n0 = fminf(t0, b0);                \
        float _m1 = fmaxf(t1, b1);                \
        float _t2 = fmaxf(t2, b2);                \
        t0 = _m0;                                 \
        t1 = fmaxf(_n0, _m1);                     \
        t2 = fmaxf(fminf(_n0, _m1), _t2);         \
    } while (0)

// ---- kernel 2: one block per (a,b) pair. MFMA 16x16x32 f16.
// A-operand = s-hat (D rows = j), B-operand = q-hat (D cols = i).
// Per-lane running top3 for its fixed column i; quad-merge via shfl_xor(16,32).
__global__ __launch_bounds__(TPB) void sim_topk_mfma(const _Float16* __restrict__ qh,
                                                     const _Float16* __restrict__ sh,
                                                     float* __restrict__ out) {
    __shared__ __align__(16) _Float16 s_lds[HWP * LDSW];   // 64512 B
    __shared__ float s_red[4];

    int pair = blockIdx.x;
    int a = pair / NB2;
    int b = pair - a * NB2;
    int tid = threadIdx.x;
    int wave = tid >> 6, lane = tid & 63;
    int m = lane & 15, quad = lane >> 4;
    const float NEG = -1e30f;

    // stage s-panel into LDS (448 rows x 8 16B-chunks), padded row stride
    {
        const float4* src = (const float4*)(sh + (size_t)b * HWP * CCH);
        for (int c = tid; c < HWP * 8; c += TPB) {
            int row = c >> 3, col = c & 7;
            *(float4*)(s_lds + row * LDSW + col * 8) = src[c];
        }
    }
    __syncthreads();

    const _Float16* qbase = qh + (size_t)a * HWP * CCH;
    float wacc = 0.f;

    // 7 i-tiles per wave: 3 dual passes + 1 single pass
    for (int pp = 0; pp < 3; ++pp) {
        int it0 = wave * 7 + pp * 2;
        int it1 = it0 + 1;
        const _Float16* q0 = qbase + (it0 * 16 + m) * CCH + quad * 8;
        const _Float16* q1 = qbase + (it1 * 16 + m) * CCH + quad * 8;
        half8 b00 = *(const half8*)(q0);
        half8 b01 = *(const half8*)(q0 + 32);
        half8 b10 = *(const half8*)(q1);
        half8 b11 = *(const half8*)(q1 + 32);
        float t00 = NEG, t01 = NEG, t02 = NEG;
        float t10 = NEG, t11 = NEG, t12 = NEG;
        for (int jt = 0; jt < NT; ++jt) {
            const _Float16* srow = s_lds + (jt * 16 + m) * LDSW + quad * 8;
            half8 a0 = *(const half8*)(srow);
            half8 a1 = *(const half8*)(srow + 32);
            f32x4 acc0 = {0.f, 0.f, 0.f, 0.f};
            f32x4 acc1 = {0.f, 0.f, 0.f, 0.f};
            acc0 = __builtin_amdgcn_mfma_f32_16x16x32_f16(a0, b00, acc0, 0, 0, 0);
            acc0 = __builtin_amdgcn_mfma_f32_16x16x32_f16(a1, b01, acc0, 0, 0, 0);
            acc1 = __builtin_amdgcn_mfma_f32_16x16x32_f16(a0, b10, acc1, 0, 0, 0);
            acc1 = __builtin_amdgcn_mfma_f32_16x16x32_f16(a1, b11, acc1, 0, 0, 0);
            if (jt == NT - 1) {
#pragma unroll
                for (int r = 0; r < 4; ++r) {
                    if (quad * 4 + r >= 9) { acc0[r] = NEG; acc1[r] = NEG; }
                }
            }
#pragma unroll
            for (int r = 0; r < 4; ++r) TOP3_INSERT(acc0[r], t00, t01, t02);
#pragma unroll
            for (int r = 0; r < 4; ++r) TOP3_INSERT(acc1[r], t10, t11, t12);
        }
        // quad-merge + accumulate (each column i appears in 4 lanes; keep quad 0)
        {
            float b0 = __shfl_xor(t00, 16), b1 = __shfl_xor(t01, 16), b2 = __shfl_xor(t02, 16);
            MERGE3(t00, t01, t02, b0, b1, b2);
            b0 = __shfl_xor(t00, 32); b1 = __shfl_xor(t01, 32); b2 = __shfl_xor(t02, 32);
            MERGE3(t00, t01, t02, b0, b1, b2);
            wacc += (quad == 0) ? (t00 + t01 + t02) : 0.f;
        }
        {
            float b0 = __shfl_xor(t10, 16), b1 = __shfl_xor(t11, 16), b2 = __shfl_xor(t12, 16);
            MERGE3(t10, t11, t12, b0, b1, b2);
            b0 = __shfl_xor(t10, 32); b1 = __shfl_xor(t11, 32); b2 = __shfl_xor(t12, 32);
            MERGE3(t10, t11, t12, b0, b1, b2);
            wacc += (quad == 0) ? (t10 + t11 + t12) : 0.f;
        }
    }
    // single pass: it = wave*7 + 6
    {
        int it0 = wave * 7 + 6;
        const _Float16* q0 = qbase + (it0 * 16 + m) * CCH + quad * 8;
        half8 b00 = *(const half8*)(q0);
        half8 b01 = *(const half8*)(q0 + 32);
        float t00 = NEG, t01 = NEG, t02 = NEG;
        for (int jt = 0; jt < NT; ++jt) {
            const _Float16* srow = s_lds + (jt * 16 + m) * LDSW + quad * 8;
            half8 a0 = *(const half8*)(srow);
            half8 a1 = *(const half8*)(srow + 32);
            f32x4 acc0 = {0.f, 0.f, 0.f, 0.f};
            acc0 = __builtin_amdgcn_mfma_f32_16x16x32_f16(a0, b00, acc0, 0, 0, 0);
            acc0 = __builtin_amdgcn_mfma_f32_16x16x32_f16(a1, b01, acc0, 0, 0, 0);
            if (jt == NT - 1) {
#pragma unroll
                for (int r = 0; r < 4; ++r) {
                    if (quad * 4 + r >= 9) acc0[r] = NEG;
                }
            }
#pragma unroll
            for (int r = 0; r < 4; ++r) TOP3_INSERT(acc0[r], t00, t01, t02);
        }
        float b0 = __shfl_xor(t00, 16), b1 = __shfl_xor(t01, 16), b2 = __shfl_xor(t02, 16);
        MERGE3(t00, t01, t02, b0, b1, b2);
        b0 = __shfl_xor(t00, 32); b1 = __shfl_xor(t01, 32); b2 = __shfl_xor(t02, 32);
        MERGE3(t00, t01, t02, b0, b1, b2);
        wacc += (quad == 0) ? (t00 + t01 + t02) : 0.f;
    }

    // wave reduce + block reduce
#pragma unroll
    for (int off = 32; off > 0; off >>= 1) wacc += __shfl_down(wacc, off);
    if (lane == 0) s_red[wave] = wacc;
    __syncthreads();
    if (tid == 0) out[pair] = s_red[0] + s_red[1] + s_red[2] + s_red[3];
}

extern "C" void kernel_launch(void* const* d_in, const int* in_sizes, int n_in,
                              void* d_out, int out_size, void* d_ws, size_t ws_size,
                              hipStream_t stream) {
    const float* x1 = (const float*)d_in[0];
    const float* x2 = (const float*)d_in[1];
    const float* m1 = (const float*)d_in[2];
    const float* m2 = (const float*)d_in[3];
    float* out = (float*)d_out;

    int B1 = in_sizes[0] / (CCH * HW);
    int B2 = in_sizes[1] / (CCH * HW);

    _Float16* qh = (_Float16*)d_ws;
    _Float16* sh = qh + (size_t)B1 * HWP * CCH;

    int n1 = B1 * HWP, n2 = B2 * HWP;
    normalize_f16_kernel<<<(n1 + TPB - 1) / TPB, TPB, 0, stream>>>(x1, m1, qh, B1);
    normalize_f16_kernel<<<(n2 + TPB - 1) / TPB, TPB, 0, stream>>>(x2, m2, sh, B2);
    sim_topk_mfma<<<B1 * B2, TPB, 0, stream>>>(qh, sh, out);
}

// Round 3
// 116.083 us; speedup vs baseline: 5.5406x; 1.0974x over previous
//
#include <hip/hip_runtime.h>
#include <math.h>

#define CCH 64
#define HW 441
#define HWP 448
#define NT 28
#define NB2 25
#define TPB 256
#define PANEL (HWP * CCH)   // 28672 halves per panel

typedef _Float16 half8 __attribute__((ext_vector_type(8)));
typedef float f32x4 __attribute__((ext_vector_type(4)));

// ---- kernel 1: fold mask + 1/norm into f16 descriptors, write in MFMA
// fragment order: panel[tile][kfrag][lane][8] where lane = quad*16 + m,
// row i = tile*16 + m, col c = kfrag*32 + quad*8 + e. Handles both tensors.
__global__ void normalize_frag_kernel(const float* __restrict__ x1,
                                      const float* __restrict__ m1,
                                      const float* __restrict__ x2,
                                      const float* __restrict__ m2,
                                      _Float16* __restrict__ qh,
                                      _Float16* __restrict__ sh,
                                      int n1rows, int nrows) {
    int idx = blockIdx.x * blockDim.x + threadIdx.x;
    if (idx >= nrows) return;
    const float* x; const float* mk; _Float16* outp; int rb;
    if (idx < n1rows) { x = x1; mk = m1; outp = qh; rb = idx; }
    else             { x = x2; mk = m2; outp = sh; rb = idx - n1rows; }
    int b = rb / HWP, i = rb - b * HWP;
    float vals[CCH];
    if (i < HW) {
        const float* xb = x + (size_t)b * CCH * HW + i;
        float ss = 0.f;
#pragma unroll
        for (int c = 0; c < CCH; ++c) { float v = xb[c * HW]; vals[c] = v; ss += v * v; }
        float scale = mk[b * HW + i] * rsqrtf(ss);
#pragma unroll
        for (int c = 0; c < CCH; ++c) vals[c] *= scale;
    } else {
#pragma unroll
        for (int c = 0; c < CCH; ++c) vals[c] = 0.f;
    }
    _Float16* pb = outp + (size_t)b * PANEL + (i >> 4) * 1024 + (i & 15) * 8;
#pragma unroll
    for (int f = 0; f < 2; ++f) {
#pragma unroll
        for (int qd = 0; qd < 4; ++qd) {
            half8 h;
#pragma unroll
            for (int e = 0; e < 8; ++e) h[e] = (_Float16)vals[f * 32 + qd * 8 + e];
            *(half8*)(pb + f * 512 + qd * 128) = h;
        }
    }
}

// branchless top-3 insert: 3 max + 2 min
#define TOP3_INSERT(v, t0, t1, t2)        \
    do {                                  \
        float _m = fmaxf(t0, v);          \
        float _c = fminf(t0, v);          \
        t0 = _m;                          \
        _m = fmaxf(t1, _c);               \
        _c = fminf(t1, _c);               \
        t1 = _m;                          \
        t2 = fmaxf(t2, _c);               \
    } while (0)

// merge two desc-sorted triples -> top3 of union in (t0,t1,t2)
#define MERGE3(t0, t1, t2, b0, b1, b2)            \
    do {                                          \
        float _m0 = fmaxf(t0, b0);                \
        float _n0 = fminf(t0, b0);                \
        float _m1 = fmaxf(t1, b1);                \
        float _t2 = fmaxf(t2, b2);                \
        t0 = _m0;                                 \
        t1 = fmaxf(_n0, _m1);                     \
        t2 = fmaxf(fminf(_n0, _m1), _t2);         \
    } while (0)

// one pass over all 28 j-tiles for NI consecutive i-tiles starting at it0.
// All fragments read directly from global (fragment-order layout, coalesced,
// L1/L2-resident). Returns this lane's top-3 sum contribution (quad 0 only).
template <int NI>
__device__ __forceinline__ float do_pass(const _Float16* __restrict__ qpanel,
                                         const _Float16* __restrict__ spanel,
                                         int it0, int lane, int quad) {
    const float NEG = -1e30f;
    half8 bf0[NI], bf1[NI];
#pragma unroll
    for (int t = 0; t < NI; ++t) {
        const _Float16* qp = qpanel + (it0 + t) * 1024 + lane * 8;
        bf0[t] = *(const half8*)qp;
        bf1[t] = *(const half8*)(qp + 512);
    }
    float t0[NI], t1[NI], t2[NI];
#pragma unroll
    for (int t = 0; t < NI; ++t) { t0[t] = NEG; t1[t] = NEG; t2[t] = NEG; }

    for (int jt = 0; jt < NT; ++jt) {
        const _Float16* sp = spanel + jt * 1024 + lane * 8;
        half8 a0 = *(const half8*)sp;
        half8 a1 = *(const half8*)(sp + 512);
        f32x4 acc[NI];
#pragma unroll
        for (int t = 0; t < NI; ++t) {
            f32x4 z = {0.f, 0.f, 0.f, 0.f};
            z = __builtin_amdgcn_mfma_f32_16x16x32_f16(a0, bf0[t], z, 0, 0, 0);
            z = __builtin_amdgcn_mfma_f32_16x16x32_f16(a1, bf1[t], z, 0, 0, 0);
            acc[t] = z;
        }
        if (jt == NT - 1) {   // j = 432 + quad*4 + r valid iff quad*4+r < 9
#pragma unroll
            for (int t = 0; t < NI; ++t) {
#pragma unroll
                for (int r = 0; r < 4; ++r)
                    if (quad * 4 + r >= 9) acc[t][r] = NEG;
            }
        }
#pragma unroll
        for (int t = 0; t < NI; ++t) {
#pragma unroll
            for (int r = 0; r < 4; ++r)
                TOP3_INSERT(acc[t][r], t0[t], t1[t], t2[t]);
        }
    }

    float res = 0.f;
#pragma unroll
    for (int t = 0; t < NI; ++t) {
        float b0 = __shfl_xor(t0[t], 16), b1 = __shfl_xor(t1[t], 16), b2 = __shfl_xor(t2[t], 16);
        MERGE3(t0[t], t1[t], t2[t], b0, b1, b2);
        b0 = __shfl_xor(t0[t], 32); b1 = __shfl_xor(t1[t], 32); b2 = __shfl_xor(t2[t], 32);
        MERGE3(t0[t], t1[t], t2[t], b0, b1, b2);
        res += t0[t] + t1[t] + t2[t];
    }
    return (quad == 0) ? res : 0.f;
}

// ---- kernel 2: one block per (a,b) pair, 4 waves, 7 i-tiles/wave (4+3 passes)
__global__ __launch_bounds__(TPB) void sim_topk_mfma(const _Float16* __restrict__ qh,
                                                     const _Float16* __restrict__ sh,
                                                     float* __restrict__ out) {
    __shared__ float s_red[4];
    int pair = blockIdx.x;
    int a = pair / NB2, b = pair - a * NB2;
    int tid = threadIdx.x, wave = tid >> 6, lane = tid & 63, quad = lane >> 4;
    const _Float16* qpanel = qh + (size_t)a * PANEL;
    const _Float16* spanel = sh + (size_t)b * PANEL;

    float wacc = do_pass<4>(qpanel, spanel, wave * 7, lane, quad)
               + do_pass<3>(qpanel, spanel, wave * 7 + 4, lane, quad);

#pragma unroll
    for (int off = 32; off > 0; off >>= 1) wacc += __shfl_down(wacc, off);
    if (lane == 0) s_red[wave] = wacc;
    __syncthreads();
    if (tid == 0) out[pair] = s_red[0] + s_red[1] + s_red[2] + s_red[3];
}

extern "C" void kernel_launch(void* const* d_in, const int* in_sizes, int n_in,
                              void* d_out, int out_size, void* d_ws, size_t ws_size,
                              hipStream_t stream) {
    const float* x1 = (const float*)d_in[0];
    const float* x2 = (const float*)d_in[1];
    const float* m1 = (const float*)d_in[2];
    const float* m2 = (const float*)d_in[3];
    float* out = (float*)d_out;

    int B1 = in_sizes[0] / (CCH * HW);
    int B2 = in_sizes[1] / (CCH * HW);

    _Float16* qh = (_Float16*)d_ws;
    _Float16* sh = qh + (size_t)B1 * PANEL;

    int n1 = B1 * HWP, ntot = (B1 + B2) * HWP;
    normalize_frag_kernel<<<(ntot + TPB - 1) / TPB, TPB, 0, stream>>>(
        x1, m1, x2, m2, qh, sh, n1, ntot);
    sim_topk_mfma<<<B1 * B2, TPB, 0, stream>>>(qh, sh, out);
}

// Round 4
// 107.427 us; speedup vs baseline: 5.9870x; 1.0806x over previous
//
#include <hip/hip_runtime.h>
#include <math.h>

#define CCH 64
#define HW 441
#define HWP 448
#define NT 28
#define NB2 25
#define PANEL (HWP * CCH)   // 28672 halves per panel

typedef _Float16 half8 __attribute__((ext_vector_type(8)));
typedef float f32x4 __attribute__((ext_vector_type(4)));

// ---- kernel 1: fold mask + 1/norm into f16 descriptors, write in MFMA
// fragment order: panel[tile][kfrag][lane][8] where lane = quad*16 + m,
// row i = tile*16 + m, col c = kfrag*32 + quad*8 + e. Handles both tensors.
__global__ void normalize_frag_kernel(const float* __restrict__ x1,
                                      const float* __restrict__ m1,
                                      const float* __restrict__ x2,
                                      const float* __restrict__ m2,
                                      _Float16* __restrict__ qh,
                                      _Float16* __restrict__ sh,
                                      int n1rows, int nrows) {
    int idx = blockIdx.x * blockDim.x + threadIdx.x;
    if (idx >= nrows) return;
    const float* x; const float* mk; _Float16* outp; int rb;
    if (idx < n1rows) { x = x1; mk = m1; outp = qh; rb = idx; }
    else             { x = x2; mk = m2; outp = sh; rb = idx - n1rows; }
    int b = rb / HWP, i = rb - b * HWP;
    float vals[CCH];
    if (i < HW) {
        const float* xb = x + (size_t)b * CCH * HW + i;
        float ss = 0.f;
#pragma unroll
        for (int c = 0; c < CCH; ++c) { float v = xb[c * HW]; vals[c] = v; ss += v * v; }
        float scale = mk[b * HW + i] * rsqrtf(ss);
#pragma unroll
        for (int c = 0; c < CCH; ++c) vals[c] *= scale;
    } else {
#pragma unroll
        for (int c = 0; c < CCH; ++c) vals[c] = 0.f;
    }
    _Float16* pb = outp + (size_t)b * PANEL + (i >> 4) * 1024 + (i & 15) * 8;
#pragma unroll
    for (int f = 0; f < 2; ++f) {
#pragma unroll
        for (int qd = 0; qd < 4; ++qd) {
            half8 h;
#pragma unroll
            for (int e = 0; e < 8; ++e) h[e] = (_Float16)vals[f * 32 + qd * 8 + e];
            *(half8*)(pb + f * 512 + qd * 128) = h;
        }
    }
}

// sorted top-3 of 4 values (9 ops, tree-shaped) merged into running sorted
// triple (7 ops). Total 16 ops per 4 values vs 20 for sequential inserts.
__device__ __forceinline__ void top3of4_merge(f32x4 v, float& t0, float& t1, float& t2) {
    float s1 = fmaxf(v[0], v[1]), n1 = fminf(v[0], v[1]);
    float s2 = fmaxf(v[2], v[3]), n2 = fminf(v[2], v[3]);
    float x = fminf(s1, s2), y = fmaxf(n1, n2);
    float b0 = fmaxf(s1, s2);          // max
    float b1 = fmaxf(x, y);            // 2nd
    float b2 = fminf(x, y);            // 3rd  (min(n1,n2) <= x always)
    // MERGE3 of sorted triples (t0,t1,t2) and (b0,b1,b2)
    float m0 = fmaxf(t0, b0), nn0 = fminf(t0, b0);
    float m1 = fmaxf(t1, b1);
    float mt2 = fmaxf(t2, b2);
    t0 = m0;
    t1 = fmaxf(nn0, m1);
    t2 = fmaxf(fminf(nn0, m1), mt2);
}

#define MERGE3(t0, t1, t2, b0, b1, b2)            \
    do {                                          \
        float _m0 = fmaxf(t0, b0);                \
        float _n0 = fminf(t0, b0);                \
        float _m1 = fmaxf(t1, b1);                \
        float _t2 = fmaxf(t2, b2);                \
        t0 = _m0;                                 \
        t1 = fmaxf(_n0, _m1);                     \
        t2 = fmaxf(fminf(_n0, _m1), _t2);         \
    } while (0)

// one pass over all 28 j-tiles for NI consecutive i-tiles.
// Fragments read directly from global (fragment-order layout, L2-resident).
template <int NI>
__device__ __forceinline__ float do_pass(const _Float16* __restrict__ qtiles,
                                         const _Float16* __restrict__ spanel,
                                         int lane, int quad) {
    const float NEG = -1e30f;
    const f32x4 FZ = {0.f, 0.f, 0.f, 0.f};
    half8 bf0[NI], bf1[NI];
#pragma unroll
    for (int t = 0; t < NI; ++t) {
        const _Float16* qp = qtiles + t * 1024 + lane * 8;
        bf0[t] = *(const half8*)qp;
        bf1[t] = *(const half8*)(qp + 512);
    }
    float t0[NI], t1[NI], t2[NI];
#pragma unroll
    for (int t = 0; t < NI; ++t) { t0[t] = NEG; t1[t] = NEG; t2[t] = NEG; }

    for (int jt = 0; jt < NT - 1; ++jt) {
        const _Float16* sp = spanel + jt * 1024 + lane * 8;
        half8 a0 = *(const half8*)sp;
        half8 a1 = *(const half8*)(sp + 512);
#pragma unroll
        for (int t = 0; t < NI; ++t) {
            f32x4 z = __builtin_amdgcn_mfma_f32_16x16x32_f16(a0, bf0[t], FZ, 0, 0, 0);
            z = __builtin_amdgcn_mfma_f32_16x16x32_f16(a1, bf1[t], z, 0, 0, 0);
            top3of4_merge(z, t0[t], t1[t], t2[t]);
        }
    }
    {   // last j-tile: rows j = 432 + quad*4 + r valid iff quad*4+r < 9
        const _Float16* sp = spanel + (NT - 1) * 1024 + lane * 8;
        half8 a0 = *(const half8*)sp;
        half8 a1 = *(const half8*)(sp + 512);
#pragma unroll
        for (int t = 0; t < NI; ++t) {
            f32x4 z = __builtin_amdgcn_mfma_f32_16x16x32_f16(a0, bf0[t], FZ, 0, 0, 0);
            z = __builtin_amdgcn_mfma_f32_16x16x32_f16(a1, bf1[t], z, 0, 0, 0);
#pragma unroll
            for (int r = 0; r < 4; ++r)
                if (quad * 4 + r >= 9) z[r] = NEG;
            top3of4_merge(z, t0[t], t1[t], t2[t]);
        }
    }

    float res = 0.f;
#pragma unroll
    for (int t = 0; t < NI; ++t) {
        float b0 = __shfl_xor(t0[t], 16), b1 = __shfl_xor(t1[t], 16), b2 = __shfl_xor(t2[t], 16);
        MERGE3(t0[t], t1[t], t2[t], b0, b1, b2);
        b0 = __shfl_xor(t0[t], 32); b1 = __shfl_xor(t1[t], 32); b2 = __shfl_xor(t2[t], 32);
        MERGE3(t0[t], t1[t], t2[t], b0, b1, b2);
        res += t0[t] + t1[t] + t2[t];
    }
    return (quad == 0) ? res : 0.f;
}

// ---- kernel 2: 4 blocks per (a,b) pair, each block = 2 waves covering 7
// i-tiles (4+3). 3200 blocks x 128 threads = 25 waves/CU for latency hiding.
__global__ __launch_bounds__(128, 6) void sim_topk_mfma(const _Float16* __restrict__ qh,
                                                        const _Float16* __restrict__ sh,
                                                        float* __restrict__ out) {
    __shared__ float s_red[2];
    int blk = blockIdx.x;
    int pair = blk >> 2, g = blk & 3;
    int a = pair / NB2, b = pair - a * NB2;
    int tid = threadIdx.x, wave = tid >> 6, lane = tid & 63, quad = lane >> 4;
    const _Float16* qtiles = qh + (size_t)a * PANEL + (size_t)g * 7 * 1024;
    const _Float16* spanel = sh + (size_t)b * PANEL;

    float wacc = (wave == 0)
                     ? do_pass<4>(qtiles, spanel, lane, quad)
                     : do_pass<3>(qtiles + 4 * 1024, spanel, lane, quad);

#pragma unroll
    for (int off = 32; off > 0; off >>= 1) wacc += __shfl_down(wacc, off);
    if (lane == 0) s_red[wave] = wacc;
    __syncthreads();
    if (tid == 0) atomicAdd(&out[pair], s_red[0] + s_red[1]);
}

extern "C" void kernel_launch(void* const* d_in, const int* in_sizes, int n_in,
                              void* d_out, int out_size, void* d_ws, size_t ws_size,
                              hipStream_t stream) {
    const float* x1 = (const float*)d_in[0];
    const float* x2 = (const float*)d_in[1];
    const float* m1 = (const float*)d_in[2];
    const float* m2 = (const float*)d_in[3];
    float* out = (float*)d_out;

    int B1 = in_sizes[0] / (CCH * HW);
    int B2 = in_sizes[1] / (CCH * HW);

    _Float16* qh = (_Float16*)d_ws;
    _Float16* sh = qh + (size_t)B1 * PANEL;

    hipMemsetAsync(d_out, 0, (size_t)out_size * sizeof(float), stream);

    int n1 = B1 * HWP, ntot = (B1 + B2) * HWP;
    normalize_frag_kernel<<<(ntot + 255) / 256, 256, 0, stream>>>(
        x1, m1, x2, m2, qh, sh, n1, ntot);
    sim_topk_mfma<<<B1 * B2 * 4, 128, 0, stream>>>(qh, sh, out);
}

// Round 6
// 101.521 us; speedup vs baseline: 6.3353x; 1.0582x over previous
//
#include <hip/hip_runtime.h>
#include <math.h>

#define CCH 64
#define HW 441
#define HWP 448
#define NT 28
#define NB2 25
#define PANEL (HWP * CCH)   // 28672 halves per panel

typedef _Float16 half8 __attribute__((ext_vector_type(8)));
typedef __fp16 h2 __attribute__((ext_vector_type(2)));
typedef float f32x4 __attribute__((ext_vector_type(4)));

// ---- kernel 1: fold mask + 1/norm into f16 descriptors, write in MFMA
// fragment order: panel[tile][kfrag][lane][8] where lane = quad*16 + m,
// row i = tile*16 + m, col c = kfrag*32 + quad*8 + e. Also zeroes d_out
// (stream-ordered before the sim kernel, which accumulates with atomics).
__global__ void normalize_frag_kernel(const float* __restrict__ x1,
                                      const float* __restrict__ m1,
                                      const float* __restrict__ x2,
                                      const float* __restrict__ m2,
                                      _Float16* __restrict__ qh,
                                      _Float16* __restrict__ sh,
                                      float* __restrict__ out, int nout,
                                      int n1rows, int nrows) {
    int idx = blockIdx.x * blockDim.x + threadIdx.x;
    if (idx < nout) out[idx] = 0.f;
    if (idx >= nrows) return;
    const float* x; const float* mk; _Float16* outp; int rb;
    if (idx < n1rows) { x = x1; mk = m1; outp = qh; rb = idx; }
    else             { x = x2; mk = m2; outp = sh; rb = idx - n1rows; }
    int b = rb / HWP, i = rb - b * HWP;
    float vals[CCH];
    if (i < HW) {
        const float* xb = x + (size_t)b * CCH * HW + i;
        float ss = 0.f;
#pragma unroll
        for (int c = 0; c < CCH; ++c) { float v = xb[c * HW]; vals[c] = v; ss += v * v; }
        float scale = mk[b * HW + i] * rsqrtf(ss);
#pragma unroll
        for (int c = 0; c < CCH; ++c) vals[c] *= scale;
    } else {
#pragma unroll
        for (int c = 0; c < CCH; ++c) vals[c] = 0.f;
    }
    _Float16* pb = outp + (size_t)b * PANEL + (i >> 4) * 1024 + (i & 15) * 8;
#pragma unroll
    for (int f = 0; f < 2; ++f) {
#pragma unroll
        for (int qd = 0; qd < 4; ++qd) {
            half8 h;
#pragma unroll
            for (int e = 0; e < 8; ++e) h[e] = (_Float16)vals[f * 32 + qd * 8 + e];
            *(half8*)(pb + f * 512 + qd * 128) = h;
        }
    }
}

static __device__ __forceinline__ h2 hmax2(h2 a, h2 b) {
    return __builtin_elementwise_max(a, b);
}
static __device__ __forceinline__ h2 hmin2(h2 a, h2 b) {
    return __builtin_elementwise_min(a, b);
}

// packed top-3 insert: lo/hi halves are two independent triples. 5 packed ops.
#define PK_INSERT(v, p0, p1, p2)           \
    do {                                   \
        h2 _m = hmax2(p0, v);              \
        h2 _c = hmin2(p0, v);              \
        p0 = _m;                           \
        _m = hmax2(p1, _c);                \
        _c = hmin2(p1, _c);                \
        p1 = _m;                           \
        p2 = hmax2(p2, _c);                \
    } while (0)

// merge two desc-sorted f32 triples -> top3 of union in (t0,t1,t2)
#define MERGE3(t0, t1, t2, b0, b1, b2)            \
    do {                                          \
        float _m0 = fmaxf(t0, b0);                \
        float _n0 = fminf(t0, b0);                \
        float _m1 = fmaxf(t1, b1);                \
        float _t2 = fmaxf(t2, b2);                \
        t0 = _m0;                                 \
        t1 = fmaxf(_n0, _m1);                     \
        t2 = fmaxf(fminf(_n0, _m1), _t2);         \
    } while (0)

// one pass over all 28 j-tiles for NI consecutive i-tiles.
// s-frags prefetched one jt ahead (register double-buffer); last tile peeled
// for the j-mask. Returns this lane's contribution (quad 0 lanes only).
template <int NI>
__device__ __forceinline__ float do_pass(const _Float16* __restrict__ qtiles,
                                         const _Float16* __restrict__ spanel,
                                         int lane, int quad) {
    const float NEG = -1e30f;
    const f32x4 FZ = {0.f, 0.f, 0.f, 0.f};
    const h2 NEGH = {(__fp16)-65504.f, (__fp16)-65504.f};
    half8 bf0[NI], bf1[NI];
#pragma unroll
    for (int t = 0; t < NI; ++t) {
        const _Float16* qp = qtiles + t * 1024 + lane * 8;
        bf0[t] = *(const half8*)qp;
        bf1[t] = *(const half8*)(qp + 512);
    }
    h2 p0[NI], p1[NI], p2[NI];
#pragma unroll
    for (int t = 0; t < NI; ++t) { p0[t] = NEGH; p1[t] = NEGH; p2[t] = NEGH; }

    const _Float16* sp = spanel + lane * 8;
    half8 a0 = *(const half8*)sp;
    half8 a1 = *(const half8*)(sp + 512);

    for (int jt = 0; jt < NT - 1; ++jt) {
        const _Float16* np = sp + (jt + 1) * 1024;
        half8 na0 = *(const half8*)np;
        half8 na1 = *(const half8*)(np + 512);
#pragma unroll
        for (int t = 0; t < NI; ++t) {
            f32x4 z = __builtin_amdgcn_mfma_f32_16x16x32_f16(a0, bf0[t], FZ, 0, 0, 0);
            z = __builtin_amdgcn_mfma_f32_16x16x32_f16(a1, bf1[t], z, 0, 0, 0);
            h2 c02 = __builtin_amdgcn_cvt_pkrtz(z[0], z[2]);
            h2 c13 = __builtin_amdgcn_cvt_pkrtz(z[1], z[3]);
            PK_INSERT(c02, p0[t], p1[t], p2[t]);
            PK_INSERT(c13, p0[t], p1[t], p2[t]);
        }
        a0 = na0;
        a1 = na1;
    }
    {   // last j-tile: rows j = 432 + quad*4 + r valid iff quad*4+r < 9
#pragma unroll
        for (int t = 0; t < NI; ++t) {
            f32x4 z = __builtin_amdgcn_mfma_f32_16x16x32_f16(a0, bf0[t], FZ, 0, 0, 0);
            z = __builtin_amdgcn_mfma_f32_16x16x32_f16(a1, bf1[t], z, 0, 0, 0);
#pragma unroll
            for (int r = 0; r < 4; ++r)
                if (quad * 4 + r >= 9) z[r] = NEG;
            h2 c02 = __builtin_amdgcn_cvt_pkrtz(z[0], z[2]);
            h2 c13 = __builtin_amdgcn_cvt_pkrtz(z[1], z[3]);
            PK_INSERT(c02, p0[t], p1[t], p2[t]);
            PK_INSERT(c13, p0[t], p1[t], p2[t]);
        }
    }

    float res = 0.f;
#pragma unroll
    for (int t = 0; t < NI; ++t) {
        // merge lo-half triple with hi-half triple in f32
        float t0 = (float)p0[t][0], t1 = (float)p1[t][0], t2 = (float)p2[t][0];
        float b0 = (float)p0[t][1], b1 = (float)p1[t][1], b2 = (float)p2[t][1];
        MERGE3(t0, t1, t2, b0, b1, b2);
        // cross-quad merges (each column i lives in 4 lanes)
        b0 = __shfl_xor(t0, 16); b1 = __shfl_xor(t1, 16); b2 = __shfl_xor(t2, 16);
        MERGE3(t0, t1, t2, b0, b1, b2);
        b0 = __shfl_xor(t0, 32); b1 = __shfl_xor(t1, 32); b2 = __shfl_xor(t2, 32);
        MERGE3(t0, t1, t2, b0, b1, b2);
        res += t0 + t1 + t2;
    }
    return (quad == 0) ? res : 0.f;
}

// ---- kernel 2: 4 blocks per (a,b) pair, 2 waves each (NI=4 + NI=3).
// No LDS, no barrier: each wave atomically accumulates its partial.
__global__ __launch_bounds__(128, 4) void sim_topk_mfma(const _Float16* __restrict__ qh,
                                                        const _Float16* __restrict__ sh,
                                                        float* __restrict__ out) {
    int blk = blockIdx.x;
    int pair = blk >> 2, g = blk & 3;
    int a = pair / NB2, b = pair - a * NB2;
    int tid = threadIdx.x, wave = tid >> 6, lane = tid & 63, quad = lane >> 4;
    const _Float16* qtiles = qh + (size_t)a * PANEL + (size_t)g * 7 * 1024;
    const _Float16* spanel = sh + (size_t)b * PANEL;

    float wacc = (wave == 0)
                     ? do_pass<4>(qtiles, spanel, lane, quad)
                     : do_pass<3>(qtiles + 4 * 1024, spanel, lane, quad);

#pragma unroll
    for (int off = 32; off > 0; off >>= 1) wacc += __shfl_down(wacc, off);
    if (lane == 0) atomicAdd(&out[pair], wacc);
}

extern "C" void kernel_launch(void* const* d_in, const int* in_sizes, int n_in,
                              void* d_out, int out_size, void* d_ws, size_t ws_size,
                              hipStream_t stream) {
    const float* x1 = (const float*)d_in[0];
    const float* x2 = (const float*)d_in[1];
    const float* m1 = (const float*)d_in[2];
    const float* m2 = (const float*)d_in[3];
    float* out = (float*)d_out;

    int B1 = in_sizes[0] / (CCH * HW);
    int B2 = in_sizes[1] / (CCH * HW);

    _Float16* qh = (_Float16*)d_ws;
    _Float16* sh = qh + (size_t)B1 * PANEL;

    int n1 = B1 * HWP, ntot = (B1 + B2) * HWP;
    normalize_frag_kernel<<<(ntot + 255) / 256, 256, 0, stream>>>(
        x1, m1, x2, m2, qh, sh, out, B1 * B2, n1, ntot);
    sim_topk_mfma<<<B1 * B2 * 4, 128, 0, stream>>>(qh, sh, out);
}

// Round 7
// 99.942 us; speedup vs baseline: 6.4355x; 1.0158x over previous
//
#include <hip/hip_runtime.h>
#include <math.h>

#define CCH 64
#define HW 441
#define HWP 448
#define NT 28
#define NB2 25
#define PANEL (HWP * CCH)   // 28672 halves per panel

typedef _Float16 half8 __attribute__((ext_vector_type(8)));
typedef __fp16 h2 __attribute__((ext_vector_type(2)));
typedef float f32x4 __attribute__((ext_vector_type(4)));

// ---- kernel 1: fold mask + 1/norm into f16 descriptors, write in MFMA
// fragment order: panel[tile][kfrag][lane][8] where lane = quad*16 + m,
// row i = tile*16 + m, col c = kfrag*32 + quad*8 + e. Also zeroes d_out.
// 64-thread blocks -> ~399 blocks spread across all CUs.
__global__ __launch_bounds__(64) void normalize_frag_kernel(
        const float* __restrict__ x1, const float* __restrict__ m1,
        const float* __restrict__ x2, const float* __restrict__ m2,
        _Float16* __restrict__ qh, _Float16* __restrict__ sh,
        float* __restrict__ out, int nout, int n1rows, int nrows) {
    int idx = blockIdx.x * blockDim.x + threadIdx.x;
    if (idx < nout) out[idx] = 0.f;
    if (idx >= nrows) return;
    const float* x; const float* mk; _Float16* outp; int rb;
    if (idx < n1rows) { x = x1; mk = m1; outp = qh; rb = idx; }
    else             { x = x2; mk = m2; outp = sh; rb = idx - n1rows; }
    int b = rb / HWP, i = rb - b * HWP;
    float vals[CCH];
    if (i < HW) {
        const float* xb = x + (size_t)b * CCH * HW + i;
        float ss = 0.f;
#pragma unroll
        for (int c = 0; c < CCH; ++c) { float v = xb[c * HW]; vals[c] = v; ss += v * v; }
        float scale = mk[b * HW + i] * rsqrtf(ss);
#pragma unroll
        for (int c = 0; c < CCH; ++c) vals[c] *= scale;
    } else {
#pragma unroll
        for (int c = 0; c < CCH; ++c) vals[c] = 0.f;
    }
    _Float16* pb = outp + (size_t)b * PANEL + (i >> 4) * 1024 + (i & 15) * 8;
#pragma unroll
    for (int f = 0; f < 2; ++f) {
#pragma unroll
        for (int qd = 0; qd < 4; ++qd) {
            half8 h;
#pragma unroll
            for (int e = 0; e < 8; ++e) h[e] = (_Float16)vals[f * 32 + qd * 8 + e];
            *(half8*)(pb + f * 512 + qd * 128) = h;
        }
    }
}

static __device__ __forceinline__ h2 hmax2(h2 a, h2 b) {
    return __builtin_elementwise_max(a, b);
}
static __device__ __forceinline__ h2 hmin2(h2 a, h2 b) {
    return __builtin_elementwise_min(a, b);
}

// packed top-3 insert: lo/hi halves are two independent triples. 5 packed ops.
#define PK_INSERT(v, p0, p1, p2)           \
    do {                                   \
        h2 _m = hmax2(p0, v);              \
        h2 _c = hmin2(p0, v);              \
        p0 = _m;                           \
        _m = hmax2(p1, _c);                \
        _c = hmin2(p1, _c);                \
        p1 = _m;                           \
        p2 = hmax2(p2, _c);                \
    } while (0)

// merge two desc-sorted f32 triples -> top3 of union in (t0,t1,t2)
#define MERGE3(t0, t1, t2, b0, b1, b2)            \
    do {                                          \
        float _m0 = fmaxf(t0, b0);                \
        float _n0 = fminf(t0, b0);                \
        float _m1 = fmaxf(t1, b1);                \
        float _t2 = fmaxf(t2, b2);                \
        t0 = _m0;                                 \
        t1 = fmaxf(_n0, _m1);                     \
        t2 = fmaxf(fminf(_n0, _m1), _t2);         \
    } while (0)

// one pass over all 28 j-tiles for NI=7 consecutive i-tiles, 2-deep s-frag
// prefetch. Last tile peeled for the j-mask. Returns this lane's
// contribution (quad-0 lanes only).
template <int NI>
__device__ __forceinline__ float do_pass(const _Float16* __restrict__ qtiles,
                                         const _Float16* __restrict__ spanel,
                                         int lane, int quad) {
    const float NEG = -1e30f;
    const f32x4 FZ = {0.f, 0.f, 0.f, 0.f};
    const h2 NEGH = {(__fp16)-65504.f, (__fp16)-65504.f};
    half8 bf0[NI], bf1[NI];
#pragma unroll
    for (int t = 0; t < NI; ++t) {
        const _Float16* qp = qtiles + t * 1024 + lane * 8;
        bf0[t] = *(const half8*)qp;
        bf1[t] = *(const half8*)(qp + 512);
    }
    h2 p0[NI], p1[NI], p2[NI];
#pragma unroll
    for (int t = 0; t < NI; ++t) { p0[t] = NEGH; p1[t] = NEGH; p2[t] = NEGH; }

    const _Float16* sp = spanel + lane * 8;
    half8 c0 = *(const half8*)sp;              // jt 0
    half8 c1 = *(const half8*)(sp + 512);
    half8 n0 = *(const half8*)(sp + 1024);     // jt 1
    half8 n1 = *(const half8*)(sp + 1024 + 512);

    for (int jt = 0; jt < NT - 1; ++jt) {
        int pf = (jt + 2 < NT) ? jt + 2 : NT - 1;   // clamped 2-deep prefetch
        const _Float16* pp = sp + pf * 1024;
        half8 f0 = *(const half8*)pp;
        half8 f1 = *(const half8*)(pp + 512);
#pragma unroll
        for (int t = 0; t < NI; ++t) {
            f32x4 z = __builtin_amdgcn_mfma_f32_16x16x32_f16(c0, bf0[t], FZ, 0, 0, 0);
            z = __builtin_amdgcn_mfma_f32_16x16x32_f16(c1, bf1[t], z, 0, 0, 0);
            h2 c02 = __builtin_amdgcn_cvt_pkrtz(z[0], z[2]);
            h2 c13 = __builtin_amdgcn_cvt_pkrtz(z[1], z[3]);
            PK_INSERT(c02, p0[t], p1[t], p2[t]);
            PK_INSERT(c13, p0[t], p1[t], p2[t]);
        }
        c0 = n0; c1 = n1; n0 = f0; n1 = f1;
    }
    {   // last j-tile (c0,c1): rows j = 432 + quad*4 + r valid iff quad*4+r < 9
#pragma unroll
        for (int t = 0; t < NI; ++t) {
            f32x4 z = __builtin_amdgcn_mfma_f32_16x16x32_f16(c0, bf0[t], FZ, 0, 0, 0);
            z = __builtin_amdgcn_mfma_f32_16x16x32_f16(c1, bf1[t], z, 0, 0, 0);
#pragma unroll
            for (int r = 0; r < 4; ++r)
                if (quad * 4 + r >= 9) z[r] = NEG;
            h2 c02 = __builtin_amdgcn_cvt_pkrtz(z[0], z[2]);
            h2 c13 = __builtin_amdgcn_cvt_pkrtz(z[1], z[3]);
            PK_INSERT(c02, p0[t], p1[t], p2[t]);
            PK_INSERT(c13, p0[t], p1[t], p2[t]);
        }
    }

    float res = 0.f;
#pragma unroll
    for (int t = 0; t < NI; ++t) {
        float t0 = (float)p0[t][0], t1 = (float)p1[t][0], t2 = (float)p2[t][0];
        float b0 = (float)p0[t][1], b1 = (float)p1[t][1], b2 = (float)p2[t][1];
        MERGE3(t0, t1, t2, b0, b1, b2);
        b0 = __shfl_xor(t0, 16); b1 = __shfl_xor(t1, 16); b2 = __shfl_xor(t2, 16);
        MERGE3(t0, t1, t2, b0, b1, b2);
        b0 = __shfl_xor(t0, 32); b1 = __shfl_xor(t1, 32); b2 = __shfl_xor(t2, 32);
        MERGE3(t0, t1, t2, b0, b1, b2);
        res += t0 + t1 + t2;
    }
    return (quad == 0) ? res : 0.f;
}

// ---- kernel 2: 2 blocks per (a,b) pair, 2 waves each; wave owns 7 i-tiles
// (group = (blk&1)*2 + wave). No LDS/barrier; per-wave atomicAdd.
__global__ __launch_bounds__(128, 4) void sim_topk_mfma(const _Float16* __restrict__ qh,
                                                        const _Float16* __restrict__ sh,
                                                        float* __restrict__ out) {
    int blk = blockIdx.x;
    int pair = blk >> 1, g = blk & 1;
    int a = pair / NB2, b = pair - a * NB2;
    int tid = threadIdx.x, wave = tid >> 6, lane = tid & 63, quad = lane >> 4;
    int group = g * 2 + wave;   // 0..3, each covers 7 i-tiles
    const _Float16* qtiles = qh + (size_t)a * PANEL + (size_t)group * 7 * 1024;
    const _Float16* spanel = sh + (size_t)b * PANEL;

    float wacc = do_pass<7>(qtiles, spanel, lane, quad);

#pragma unroll
    for (int off = 32; off > 0; off >>= 1) wacc += __shfl_down(wacc, off);
    if (lane == 0) atomicAdd(&out[pair], wacc);
}

extern "C" void kernel_launch(void* const* d_in, const int* in_sizes, int n_in,
                              void* d_out, int out_size, void* d_ws, size_t ws_size,
                              hipStream_t stream) {
    const float* x1 = (const float*)d_in[0];
    const float* x2 = (const float*)d_in[1];
    const float* m1 = (const float*)d_in[2];
    const float* m2 = (const float*)d_in[3];
    float* out = (float*)d_out;

    int B1 = in_sizes[0] / (CCH * HW);
    int B2 = in_sizes[1] / (CCH * HW);

    _Float16* qh = (_Float16*)d_ws;
    _Float16* sh = qh + (size_t)B1 * PANEL;

    int n1 = B1 * HWP, ntot = (B1 + B2) * HWP;
    normalize_frag_kernel<<<(ntot + 63) / 64, 64, 0, stream>>>(
        x1, m1, x2, m2, qh, sh, out, B1 * B2, n1, ntot);
    sim_topk_mfma<<<B1 * B2 * 2, 128, 0, stream>>>(qh, sh, out);
}

// Round 8
// 99.157 us; speedup vs baseline: 6.4864x; 1.0079x over previous
//
#include <hip/hip_runtime.h>
#include <math.h>

#define CCH 64
#define HW 441
#define HWP 448
#define NT 28
#define NB2 25
#define PANEL (HWP * CCH)   // 28672 halves per panel
#define NI 4                // i-tiles per wave (7 groups x 4 = 28)

typedef _Float16 half8 __attribute__((ext_vector_type(8)));
typedef __fp16 h2 __attribute__((ext_vector_type(2)));
typedef float f32x4 __attribute__((ext_vector_type(4)));

// ---- kernel 1: fold mask + 1/norm into f16 descriptors, write in MFMA
// fragment order: panel[tile][kfrag][lane][8] where lane = quad*16 + m,
// row i = tile*16 + m, col c = kfrag*32 + quad*8 + e. Also zeroes d_out.
__global__ __launch_bounds__(64) void normalize_frag_kernel(
        const float* __restrict__ x1, const float* __restrict__ m1,
        const float* __restrict__ x2, const float* __restrict__ m2,
        _Float16* __restrict__ qh, _Float16* __restrict__ sh,
        float* __restrict__ out, int nout, int n1rows, int nrows) {
    int idx = blockIdx.x * blockDim.x + threadIdx.x;
    if (idx < nout) out[idx] = 0.f;
    if (idx >= nrows) return;
    const float* x; const float* mk; _Float16* outp; int rb;
    if (idx < n1rows) { x = x1; mk = m1; outp = qh; rb = idx; }
    else             { x = x2; mk = m2; outp = sh; rb = idx - n1rows; }
    int b = rb / HWP, i = rb - b * HWP;
    float vals[CCH];
    if (i < HW) {
        const float* xb = x + (size_t)b * CCH * HW + i;
        float ss = 0.f;
#pragma unroll
        for (int c = 0; c < CCH; ++c) { float v = xb[c * HW]; vals[c] = v; ss += v * v; }
        float scale = mk[b * HW + i] * rsqrtf(ss);
#pragma unroll
        for (int c = 0; c < CCH; ++c) vals[c] *= scale;
    } else {
#pragma unroll
        for (int c = 0; c < CCH; ++c) vals[c] = 0.f;
    }
    _Float16* pb = outp + (size_t)b * PANEL + (i >> 4) * 1024 + (i & 15) * 8;
#pragma unroll
    for (int f = 0; f < 2; ++f) {
#pragma unroll
        for (int qd = 0; qd < 4; ++qd) {
            half8 h;
#pragma unroll
            for (int e = 0; e < 8; ++e) h[e] = (_Float16)vals[f * 32 + qd * 8 + e];
            *(half8*)(pb + f * 512 + qd * 128) = h;
        }
    }
}

static __device__ __forceinline__ h2 hmax2(h2 a, h2 b) {
    return __builtin_elementwise_max(a, b);
}
static __device__ __forceinline__ h2 hmin2(h2 a, h2 b) {
    return __builtin_elementwise_min(a, b);
}

// packed top-3 insert: lo/hi halves are two independent triples. 5 packed ops.
#define PK_INSERT(v, p0, p1, p2)           \
    do {                                   \
        h2 _m = hmax2(p0, v);              \
        h2 _c = hmin2(p0, v);              \
        p0 = _m;                           \
        _m = hmax2(p1, _c);                \
        _c = hmin2(p1, _c);                \
        p1 = _m;                           \
        p2 = hmax2(p2, _c);                \
    } while (0)

// merge two desc-sorted f32 triples -> top3 of union in (t0,t1,t2)
#define MERGE3(t0, t1, t2, b0, b1, b2)            \
    do {                                          \
        float _m0 = fmaxf(t0, b0);                \
        float _n0 = fminf(t0, b0);                \
        float _m1 = fmaxf(t1, b1);                \
        float _t2 = fmaxf(t2, b2);                \
        t0 = _m0;                                 \
        t1 = fmaxf(_n0, _m1);                     \
        t2 = fmaxf(fminf(_n0, _m1), _t2);         \
    } while (0)

// Sweep nfull full j-tiles (plus one masked tile if MASKED) for NI i-tiles.
// Outputs per-column desc-sorted triples (identical across quads after the
// cross-quad merges): column = tile t, row index m = lane&15.
template <bool MASKED>
__device__ __forceinline__ void do_pass_j(const _Float16* __restrict__ qtiles,
                                          const _Float16* __restrict__ spanel,
                                          int jt0, int nfull, int lane, int quad,
                                          float (&t0)[NI], float (&t1)[NI], float (&t2)[NI]) {
    const float NEG = -1e30f;
    const f32x4 FZ = {0.f, 0.f, 0.f, 0.f};
    const h2 NEGH = {(__fp16)-65504.f, (__fp16)-65504.f};
    half8 bf0[NI], bf1[NI];
#pragma unroll
    for (int t = 0; t < NI; ++t) {
        const _Float16* qp = qtiles + t * 1024 + lane * 8;
        bf0[t] = *(const half8*)qp;
        bf1[t] = *(const half8*)(qp + 512);
    }
    h2 p0[NI], p1[NI], p2[NI];
#pragma unroll
    for (int t = 0; t < NI; ++t) { p0[t] = NEGH; p1[t] = NEGH; p2[t] = NEGH; }

    const _Float16* sp = spanel + (size_t)jt0 * 1024 + lane * 8;
    half8 c0 = *(const half8*)sp;
    half8 c1 = *(const half8*)(sp + 512);

    for (int jt = 0; jt < nfull; ++jt) {
        // prefetch next tile (clamped; last iter re-reads current)
        int nx = (jt + 1 < nfull + (MASKED ? 1 : 0)) ? jt + 1 : jt;
        const _Float16* np = sp + (size_t)nx * 1024;
        half8 n0 = *(const half8*)np;
        half8 n1 = *(const half8*)(np + 512);
#pragma unroll
        for (int t = 0; t < NI; ++t) {
            f32x4 z = __builtin_amdgcn_mfma_f32_16x16x32_f16(c0, bf0[t], FZ, 0, 0, 0);
            z = __builtin_amdgcn_mfma_f32_16x16x32_f16(c1, bf1[t], z, 0, 0, 0);
            h2 c02 = __builtin_amdgcn_cvt_pkrtz(z[0], z[2]);
            h2 c13 = __builtin_amdgcn_cvt_pkrtz(z[1], z[3]);
            PK_INSERT(c02, p0[t], p1[t], p2[t]);
            PK_INSERT(c13, p0[t], p1[t], p2[t]);
        }
        c0 = n0; c1 = n1;
    }
    if (MASKED) {   // global tile 27: rows j = 432+quad*4+r valid iff quad*4+r < 9
#pragma unroll
        for (int t = 0; t < NI; ++t) {
            f32x4 z = __builtin_amdgcn_mfma_f32_16x16x32_f16(c0, bf0[t], FZ, 0, 0, 0);
            z = __builtin_amdgcn_mfma_f32_16x16x32_f16(c1, bf1[t], z, 0, 0, 0);
#pragma unroll
            for (int r = 0; r < 4; ++r)
                if (quad * 4 + r >= 9) z[r] = NEG;
            h2 c02 = __builtin_amdgcn_cvt_pkrtz(z[0], z[2]);
            h2 c13 = __builtin_amdgcn_cvt_pkrtz(z[1], z[3]);
            PK_INSERT(c02, p0[t], p1[t], p2[t]);
            PK_INSERT(c13, p0[t], p1[t], p2[t]);
        }
    }

#pragma unroll
    for (int t = 0; t < NI; ++t) {
        // lo/hi stream merge in f32
        float a0 = (float)p0[t][0], a1 = (float)p1[t][0], a2 = (float)p2[t][0];
        float b0 = (float)p0[t][1], b1 = (float)p1[t][1], b2 = (float)p2[t][1];
        MERGE3(a0, a1, a2, b0, b1, b2);
        // cross-quad merges: each column lives in 4 lanes (quads)
        b0 = __shfl_xor(a0, 16); b1 = __shfl_xor(a1, 16); b2 = __shfl_xor(a2, 16);
        MERGE3(a0, a1, a2, b0, b1, b2);
        b0 = __shfl_xor(a0, 32); b1 = __shfl_xor(a1, 32); b2 = __shfl_xor(a2, 32);
        MERGE3(a0, a1, a2, b0, b1, b2);
        t0[t] = a0; t1[t] = a1; t2[t] = a2;
    }
}

// ---- kernel 2: 7 blocks per (a,b) pair (4 i-tiles each), 2 waves = 2 j-halves.
// Cross-half triple merge via LDS, then one atomicAdd per block.
__global__ __launch_bounds__(128, 4) void sim_topk_mfma(const _Float16* __restrict__ qh,
                                                        const _Float16* __restrict__ sh,
                                                        float* __restrict__ out) {
    __shared__ float s_tri[2][NI][16][3];   // 1536 B
    int blk = blockIdx.x;
    int pair = blk / 7, g = blk - pair * 7;
    int a = pair / NB2, b = pair - a * NB2;
    int tid = threadIdx.x, wave = tid >> 6, lane = tid & 63;
    int m = lane & 15, quad = lane >> 4;
    const _Float16* qtiles = qh + (size_t)a * PANEL + (size_t)g * NI * 1024;
    const _Float16* spanel = sh + (size_t)b * PANEL;

    float t0[NI], t1[NI], t2[NI];
    if (wave == 0)
        do_pass_j<false>(qtiles, spanel, 0, 14, lane, quad, t0, t1, t2);
    else
        do_pass_j<true>(qtiles, spanel, 14, 13, lane, quad, t0, t1, t2);

    if (quad == 0) {
#pragma unroll
        for (int t = 0; t < NI; ++t) {
            s_tri[wave][t][m][0] = t0[t];
            s_tri[wave][t][m][1] = t1[t];
            s_tri[wave][t][m][2] = t2[t];
        }
    }
    __syncthreads();

    if (wave == 0) {
        // 64 lanes <-> 64 columns: t = lane>>4, m = lane&15
        int t = quad;
        float a0 = s_tri[0][t][m][0], a1 = s_tri[0][t][m][1], a2 = s_tri[0][t][m][2];
        float b0 = s_tri[1][t][m][0], b1 = s_tri[1][t][m][1], b2 = s_tri[1][t][m][2];
        MERGE3(a0, a1, a2, b0, b1, b2);
        float r = a0 + a1 + a2;
#pragma unroll
        for (int off = 32; off > 0; off >>= 1) r += __shfl_down(r, off);
        if (lane == 0) atomicAdd(&out[pair], r);
    }
}

extern "C" void kernel_launch(void* const* d_in, const int* in_sizes, int n_in,
                              void* d_out, int out_size, void* d_ws, size_t ws_size,
                              hipStream_t stream) {
    const float* x1 = (const float*)d_in[0];
    const float* x2 = (const float*)d_in[1];
    const float* m1 = (const float*)d_in[2];
    const float* m2 = (const float*)d_in[3];
    float* out = (float*)d_out;

    int B1 = in_sizes[0] / (CCH * HW);
    int B2 = in_sizes[1] / (CCH * HW);

    _Float16* qh = (_Float16*)d_ws;
    _Float16* sh = qh + (size_t)B1 * PANEL;

    int n1 = B1 * HWP, ntot = (B1 + B2) * HWP;
    normalize_frag_kernel<<<(ntot + 63) / 64, 64, 0, stream>>>(
        x1, m1, x2, m2, qh, sh, out, B1 * B2, n1, ntot);
    sim_topk_mfma<<<B1 * B2 * 7, 128, 0, stream>>>(qh, sh, out);
}